// Round 8
// baseline (592.462 us; speedup 1.0000x reference)
//
#include <hip/hip_runtime.h>
#include <cstddef>
#include <cstdint>

// ---------------- problem constants ----------------
#define cB   512
#define cV   5023
#define cS   100
#define cE   50
#define cJ   5
#define cLD  17
#define cLF  68

#define cV3    15069       // V*3
#define cNPAD  15072       // 157*96 padded N

#define OUT_V  ((size_t)cB * cV * 3)
#define OUT_L  ((size_t)cB * cLF * 3)

// ws layout (dword offsets)
#define WS_BTN    ((size_t)0)                      // 15072*96 dwords (bf16 x2)
#define WS_ATM    (WS_BTN + (size_t)cNPAD * 96)    // 512*96 dwords
#define WS_JS2    (WS_ATM + 49152)                 // 2432 floats (unused; keeps offsets)
#define WS_AREL   (WS_JS2 + 2432)                  // 512*60 floats
#define WS_YROT   (WS_AREL + 30720)                // 512 ints
#define WS_JSPART (WS_YROT + 512)                  // 314*2272 floats

typedef __attribute__((ext_vector_type(8))) short short8;
typedef __attribute__((ext_vector_type(4))) float f32x4;

// fp32 -> bf16 round-to-nearest-even
__device__ __forceinline__ unsigned short f2bf(float x) {
  unsigned int u = __float_as_uint(x);
  u = (u + 0x7fffu + ((u >> 16) & 1u)) >> 16;
  return (unsigned short)u;
}

// ---------------- rodrigues (matches jax reference in fp32) ----------------
__device__ __forceinline__ void rodrigues9(float rx, float ry, float rz, float* R) {
  float a0 = rx + 1e-8f, a1 = ry + 1e-8f, a2 = rz + 1e-8f;
  float angle = sqrtf(a0 * a0 + a1 * a1 + a2 * a2);
  float inv = 1.0f / angle;
  float x = rx * inv, y = ry * inv, z = rz * inv;
  float s = sinf(angle), c = cosf(angle);
  float t = 1.0f - c;
  float xy = x * y, xz = x * z, yz = y * z;
  R[0] = 1.0f - t * (y * y + z * z);
  R[1] = -s * z + t * xy;
  R[2] =  s * y + t * xz;
  R[3] =  s * z + t * xy;
  R[4] = 1.0f - t * (x * x + z * z);
  R[5] = -s * x + t * yz;
  R[6] = -s * y + t * xz;
  R[7] =  s * x + t * yz;
  R[8] = 1.0f - t * (x * x + y * y);
}

// ---------------- k_aux (r5 split version): blocks 0..313 JS partials (16 v);
// 314..549 bf16 BTn rows. r6's unified variant was a ~3-6 us regression: reverted.
__global__ __launch_bounds__(512) void k_aux(
    const float* __restrict__ sd, const float* __restrict__ pd,
    const float* __restrict__ jreg, const float* __restrict__ vt,
    unsigned int* __restrict__ btn_u, float* __restrict__ JSpart) {
  __shared__ __align__(16) unsigned char sm[44032];  // sdt 64*152*4 @0; pdt 64*38*2 @38912
  float* sdt = (float*)sm;
  unsigned short* pdt = (unsigned short*)(sm + 38912);
  const int t = threadIdx.x;
  const int bid = blockIdx.x;
  if (bid < 314) {
    if (t >= 453) return;
    int c = t / 151, l = t - c * 151;
    int v0 = bid * 16;
    float acc[5] = {0.f, 0.f, 0.f, 0.f, 0.f};
#pragma unroll 8
    for (int vi = 0; vi < 16; ++vi) {
      int v = v0 + vi;
      bool ok = (v < cV);
      int vc = ok ? v : 0;
      float x;
      if (l < 150) x = ok ? sd[(size_t)(v * 3 + c) * 150 + l] : 0.f;
      else         x = ok ? vt[v * 3 + c] : 0.f;
#pragma unroll
      for (int j = 0; j < 5; ++j)
        acc[j] = fmaf(jreg[j * cV + vc], x, acc[j]);
    }
#pragma unroll
    for (int j = 0; j < 5; ++j)
      JSpart[(size_t)bid * 2272 + (j * 3 + c) * 151 + l] = acc[j];
  } else {
    const int n0 = (bid - 314) * 64;
    // sd rows (linear, coalesced)
    for (int idx = t; idx < 9600; idx += 512) {
      size_t g = (size_t)n0 * 150 + idx;
      float v = (g < (size_t)cV3 * 150) ? sd[g] : 0.f;
      int row = idx / 150, col = idx - row * 150;
      sdt[row * 152 + col] = v;
    }
    // pd columns (coalesced over n)
    for (int e = t; e < 2304; e += 512) {
      int kk = e >> 6, ln = e & 63;
      int n = n0 + ln;
      pdt[ln * 38 + kk] = f2bf((n < cV3) ? pd[(size_t)kk * cV3 + n] : 0.f);
    }
    __syncthreads();
    // emit BTn rows (96 dwords each), coalesced
    for (int e = t; e < 6144; e += 512) {
      int row = e / 96, d = e - row * 96;
      int n = n0 + row;
      if (n < cNPAD) {
        unsigned int wv;
        if (d < 75) {
          wv = (unsigned int)f2bf(sdt[row * 152 + 2 * d]) |
               ((unsigned int)f2bf(sdt[row * 152 + 2 * d + 1]) << 16);
        } else if (d < 93) {
          int p = (d - 75) * 2;
          wv = (unsigned int)pdt[row * 38 + p] |
               ((unsigned int)pdt[row * 38 + p + 1] << 16);
        } else {
          wv = 0u;
        }
        btn_u[(size_t)n * 96 + d] = wv;
      }
    }
  }
}

// ---------------- k_batch: JS reduction FUSED IN (k_jsred launch deleted; 5->4
// launches — testing the launch-boundary-overhead theory). Each of 16 blocks
// redundantly reduces JSpart (2.7 MB, L2/L3-served, ~2 us) into js2 LDS, then
// proceeds exactly as before: joints, rot mats, chain, A_rel, y_rot, ATm rows.
__global__ __launch_bounds__(256) void k_batch(
    const float* __restrict__ shp, const float* __restrict__ expr,
    const float* __restrict__ pose, const float* __restrict__ eyep,
    const float* __restrict__ JSpart, float* __restrict__ Arel,
    int* __restrict__ yrot, unsigned int* __restrict__ atm_u) {
  __shared__ float js2[151 * 16];
  __shared__ float sb[32 * 153];
  __shared__ float pfs[32 * 36];
  const int t = threadIdx.x;
  const int b0 = blockIdx.x * 32;
  // stage betas (independent of reduction; same barrier covers all)
  for (int e = t; e < 3200; e += 256) {
    int bl = e / 100, l = e - bl * 100;
    sb[bl * 153 + l] = shp[(size_t)(b0 + bl) * 100 + l];
  }
  for (int e = t; e < 1600; e += 256) {
    int bl = e / 50, l = e - bl * 50;
    sb[bl * 153 + 100 + l] = expr[(size_t)(b0 + bl) * 50 + l];
  }
  // inline JS reduction: thread t owns elements e = t, t+256, ... (coalesced
  // across lanes per p); serial sum over 314 partials, registers only.
  for (int e = t; e < 2265; e += 256) {
    float s = 0.f;
#pragma unroll 2
    for (int p = 0; p < 314; ++p)
      s += JSpart[(size_t)p * 2272 + e];
    int jc = e / 151, l = e - jc * 151;
    js2[l * 16 + jc] = s;
  }
  __syncthreads();

  if (t < 32) {
    int b = b0 + t;
    float jnt[5][3];
    {
      const f32x4* J4 = (const f32x4*)(js2 + 150 * 16);
      f32x4 A = J4[0], Bq = J4[1], Cq = J4[2], Dq = J4[3];
      jnt[0][0] = A.x;  jnt[0][1] = A.y;  jnt[0][2] = A.z;
      jnt[1][0] = A.w;  jnt[1][1] = Bq.x; jnt[1][2] = Bq.y;
      jnt[2][0] = Bq.z; jnt[2][1] = Bq.w; jnt[2][2] = Cq.x;
      jnt[3][0] = Cq.y; jnt[3][1] = Cq.z; jnt[3][2] = Cq.w;
      jnt[4][0] = Dq.x; jnt[4][1] = Dq.y; jnt[4][2] = Dq.z;
    }
    for (int l = 0; l < 150; ++l) {
      const f32x4* J4 = (const f32x4*)(js2 + l * 16);
      f32x4 A = J4[0], Bq = J4[1], Cq = J4[2], Dq = J4[3];
      float beta = sb[t * 153 + l];
      jnt[0][0] = fmaf(beta, A.x,  jnt[0][0]);
      jnt[0][1] = fmaf(beta, A.y,  jnt[0][1]);
      jnt[0][2] = fmaf(beta, A.z,  jnt[0][2]);
      jnt[1][0] = fmaf(beta, A.w,  jnt[1][0]);
      jnt[1][1] = fmaf(beta, Bq.x, jnt[1][1]);
      jnt[1][2] = fmaf(beta, Bq.y, jnt[1][2]);
      jnt[2][0] = fmaf(beta, Bq.z, jnt[2][0]);
      jnt[2][1] = fmaf(beta, Bq.w, jnt[2][1]);
      jnt[2][2] = fmaf(beta, Cq.x, jnt[2][2]);
      jnt[3][0] = fmaf(beta, Cq.y, jnt[3][0]);
      jnt[3][1] = fmaf(beta, Cq.z, jnt[3][1]);
      jnt[3][2] = fmaf(beta, Cq.w, jnt[3][2]);
      jnt[4][0] = fmaf(beta, Dq.x, jnt[4][0]);
      jnt[4][1] = fmaf(beta, Dq.y, jnt[4][1]);
      jnt[4][2] = fmaf(beta, Dq.z, jnt[4][2]);
    }
    float fp[5][3];
    fp[0][0] = pose[b * 6 + 0]; fp[0][1] = pose[b * 6 + 1]; fp[0][2] = pose[b * 6 + 2];
    fp[1][0] = 0.f; fp[1][1] = 0.f; fp[1][2] = 0.f;
    fp[2][0] = pose[b * 6 + 3]; fp[2][1] = pose[b * 6 + 4]; fp[2][2] = pose[b * 6 + 5];
    fp[3][0] = eyep[b * 6 + 0]; fp[3][1] = eyep[b * 6 + 1]; fp[3][2] = eyep[b * 6 + 2];
    fp[4][0] = eyep[b * 6 + 3]; fp[4][1] = eyep[b * 6 + 4]; fp[4][2] = eyep[b * 6 + 5];
    float R[5][9];
#pragma unroll
    for (int j = 0; j < 5; ++j) rodrigues9(fp[j][0], fp[j][1], fp[j][2], R[j]);
#pragma unroll
    for (int j = 1; j < 5; ++j)
#pragma unroll
      for (int r = 0; r < 9; ++r) {
        float id = (r == 0 || r == 4 || r == 8) ? 1.f : 0.f;
        pfs[t * 36 + (j - 1) * 9 + r] = R[j][r] - id;
      }
    float rel[5][3];
#pragma unroll
    for (int c = 0; c < 3; ++c) {
      rel[0][c] = jnt[0][c];
      rel[1][c] = jnt[1][c] - jnt[0][c];
      rel[2][c] = jnt[2][c] - jnt[1][c];
      rel[3][c] = jnt[3][c] - jnt[1][c];
      rel[4][c] = jnt[4][c] - jnt[1][c];
    }
    float GR[5][9], Gt[5][3];
#pragma unroll
    for (int r = 0; r < 9; ++r) GR[0][r] = R[0][r];
#pragma unroll
    for (int c = 0; c < 3; ++c) Gt[0][c] = rel[0][c];
    const int par[5] = {0, 0, 1, 1, 1};
#pragma unroll
    for (int j = 1; j < 5; ++j) {
      int p = par[j];
#pragma unroll
      for (int r = 0; r < 3; ++r) {
#pragma unroll
        for (int cc = 0; cc < 3; ++cc)
          GR[j][r * 3 + cc] = GR[p][r * 3 + 0] * R[j][0 + cc] +
                              GR[p][r * 3 + 1] * R[j][3 + cc] +
                              GR[p][r * 3 + 2] * R[j][6 + cc];
        Gt[j][r] = Gt[p][r] + GR[p][r * 3 + 0] * rel[j][0] +
                              GR[p][r * 3 + 1] * rel[j][1] +
                              GR[p][r * 3 + 2] * rel[j][2];
      }
    }
#pragma unroll
    for (int j = 0; j < 5; ++j)
#pragma unroll
      for (int r = 0; r < 3; ++r) {
        float tj = Gt[j][r] - (GR[j][r * 3 + 0] * jnt[j][0] +
                               GR[j][r * 3 + 1] * jnt[j][1] +
                               GR[j][r * 3 + 2] * jnt[j][2]);
        Arel[b * 60 + j * 12 + r * 4 + 0] = GR[j][r * 3 + 0];
        Arel[b * 60 + j * 12 + r * 4 + 1] = GR[j][r * 3 + 1];
        Arel[b * 60 + j * 12 + r * 4 + 2] = GR[j][r * 3 + 2];
        Arel[b * 60 + j * 12 + r * 4 + 3] = tj;
      }
    float Ra[9], Rb[9];
    rodrigues9(fp[1][0], fp[1][1], fp[1][2], Ra);
    rodrigues9(fp[0][0], fp[0][1], fp[0][2], Rb);
    float r00 = Rb[0] * Ra[0] + Rb[1] * Ra[3] + Rb[2] * Ra[6];
    float r10 = Rb[3] * Ra[0] + Rb[4] * Ra[3] + Rb[5] * Ra[6];
    float r20 = Rb[6] * Ra[0] + Rb[7] * Ra[3] + Rb[8] * Ra[6];
    float sy = sqrtf(r00 * r00 + r10 * r10);
    float ydeg = atan2f(-r20, sy) * 57.29577951308232f;
    int y = (int)rintf(fminf(ydeg, 39.0f));
    if (y < 0) y = (y < -39) ? 78 : (39 - y);
    yrot[b] = y;
  }
  __syncthreads();

#pragma unroll
  for (int it = 0; it < 12; ++it) {
    int e = t + it * 256;
    int bl = e / 96, d = e - bl * 96;
    unsigned int wv;
    if (d < 75) {
      wv = (unsigned int)f2bf(sb[bl * 153 + 2 * d]) |
           ((unsigned int)f2bf(sb[bl * 153 + 2 * d + 1]) << 16);
    } else if (d < 93) {
      wv = (unsigned int)f2bf(pfs[bl * 36 + (d - 75) * 2]) |
           ((unsigned int)f2bf(pfs[bl * 36 + (d - 75) * 2 + 1]) << 16);
    } else {
      wv = 0u;
    }
    atm_u[(size_t)(b0 + bl) * 96 + d] = wv;
  }
}

// ---------------- k_main (r5 version, best measured): barrier-light GEMM with
// depth-3 load ring, direct-global fragments, Os-staged coalesced stores.
// 1256 blocks = 157 nb x 8 mb (nb-adjacent same-XCD), two barriers total.
__global__ __launch_bounds__(256) void k_main(
    const unsigned short* __restrict__ BTn, const unsigned short* __restrict__ ATm,
    const float* __restrict__ Arel, const float* __restrict__ vtempl,
    const float* __restrict__ lbw, float* __restrict__ out) {
  __shared__ float Pf[96 * 66];         // 25,344 B: GEMM result, [n_loc][b] transpose
  __shared__ float Os[64 * 97];         // 24,832 B: out stage, stride 97
  __shared__ float lbwT[160];           // 32 v x 5 j
  __shared__ float vtT[96];             // 32 v x 3 c

  const int bid = blockIdx.x;           // 1256 = 157 * 8
  const int nb = bid >> 3, mb = bid & 7;

  const int t = threadIdx.x;
  const int w = t >> 6, L = t & 63;
  const int wm = w >> 1, wn = w & 1;
  const int lr = L & 15, lq = L >> 4;

  // small tiles to LDS (covered by barrier 1)
  if (t < 160) {
    int vl = t / 5, j = t - vl * 5;
    int v = nb * 32 + vl;
    lbwT[t] = (v < cV) ? lbw[v * 5 + j] : 0.f;
  }
  if (t >= 160 && t < 256) {
    int e = t - 160;
    int vl = e / 3, c = e - vl * 3;
    int v = nb * 32 + vl;
    vtT[e] = (v < cV) ? vtempl[v * 3 + c] : 0.f;
  }

  // ---- GEMM: direct-global fragments, depth-3 rolling ring ----
  const unsigned short* abase = ATm + ((size_t)mb * 64 + wm * 32 + lr) * 192 + lq * 8;
  const unsigned short* bbase = BTn + ((size_t)nb * 96 + wn * 48 + lr) * 192 + lq * 8;

  f32x4 acc[2][3];
#pragma unroll
  for (int mt = 0; mt < 2; ++mt)
#pragma unroll
    for (int nt = 0; nt < 3; ++nt) acc[mt][nt] = (f32x4){0.f, 0.f, 0.f, 0.f};

  short8 A0[3], A1[3], B0[3], B1[3], B2[3];   // ring: 15 x short8 = 60 VGPR
#pragma unroll
  for (int d = 0; d < 3; ++d) {
    const int ko = d * 32;
    A0[d] = *(const short8*)(abase + ko);
    A1[d] = *(const short8*)(abase + 16 * 192 + ko);
    B0[d] = *(const short8*)(bbase + ko);
    B1[d] = *(const short8*)(bbase + 16 * 192 + ko);
    B2[d] = *(const short8*)(bbase + 32 * 192 + ko);
  }
#pragma unroll
  for (int ks = 0; ks < 6; ++ks) {
    const int d = ks % 3;                     // static after full unroll
    short8 a0 = A0[d], a1 = A1[d], b0 = B0[d], b1 = B1[d], b2 = B2[d];
    if (ks < 3) {                             // refill ring slot for ks+3
      const int ko = (ks + 3) * 32;
      A0[d] = *(const short8*)(abase + ko);
      A1[d] = *(const short8*)(abase + 16 * 192 + ko);
      B0[d] = *(const short8*)(bbase + ko);
      B1[d] = *(const short8*)(bbase + 16 * 192 + ko);
      B2[d] = *(const short8*)(bbase + 32 * 192 + ko);
    }
    acc[0][0] = __builtin_amdgcn_mfma_f32_16x16x32_bf16(a0, b0, acc[0][0], 0, 0, 0);
    acc[1][0] = __builtin_amdgcn_mfma_f32_16x16x32_bf16(a1, b0, acc[1][0], 0, 0, 0);
    acc[0][1] = __builtin_amdgcn_mfma_f32_16x16x32_bf16(a0, b1, acc[0][1], 0, 0, 0);
    acc[1][1] = __builtin_amdgcn_mfma_f32_16x16x32_bf16(a1, b1, acc[1][1], 0, 0, 0);
    acc[0][2] = __builtin_amdgcn_mfma_f32_16x16x32_bf16(a0, b2, acc[0][2], 0, 0, 0);
    acc[1][2] = __builtin_amdgcn_mfma_f32_16x16x32_bf16(a1, b2, acc[1][2], 0, 0, 0);
  }

  // ---- acc -> Pf[n_loc][b] (stride 66: conflict-free both directions) ----
#pragma unroll
  for (int mt = 0; mt < 2; ++mt)
#pragma unroll
    for (int nt = 0; nt < 3; ++nt) {
      int n_loc = wn * 48 + nt * 16 + lr;
      int m = wm * 32 + mt * 16 + lq * 4;
      *(f32x4*)(Pf + n_loc * 66 + m) = acc[mt][nt];
    }

  // ---- Arel rows: issue before the barrier; L2 latency overlaps barrier wait ----
  const int b_loc = t >> 2, part = t & 3;
  const float* qb = Arel + ((size_t)mb * 64 + b_loc) * 60;
  f32x4 ar[15];
#pragma unroll
  for (int r = 0; r < 15; ++r) ar[r] = *(const f32x4*)(qb + 4 * r);

  __syncthreads();   // barrier 1: Pf/lbwT/vtT visible

  // ---- b-major LBS epilogue -> Os ----
#pragma unroll
  for (int ii = 0; ii < 8; ++ii) {
    const int vl = part * 8 + ii;
    float px = Pf[(vl * 3 + 0) * 66 + b_loc] + vtT[vl * 3 + 0];
    float py = Pf[(vl * 3 + 1) * 66 + b_loc] + vtT[vl * 3 + 1];
    float pz = Pf[(vl * 3 + 2) * 66 + b_loc] + vtT[vl * 3 + 2];
    float o0 = 0.f, o1 = 0.f, o2 = 0.f;
#pragma unroll
    for (int j = 0; j < 5; ++j) {
      f32x4 q0 = ar[3 * j + 0], q1 = ar[3 * j + 1], q2 = ar[3 * j + 2];
      float s0 = q0.x * px + q0.y * py + q0.z * pz + q0.w;
      float s1 = q1.x * px + q1.y * py + q1.z * pz + q1.w;
      float s2 = q2.x * px + q2.y * py + q2.z * pz + q2.w;
      float wj = lbwT[vl * 5 + j];
      o0 = fmaf(wj, s0, o0);
      o1 = fmaf(wj, s1, o1);
      o2 = fmaf(wj, s2, o2);
    }
    Os[b_loc * 97 + vl * 3 + 0] = o0;
    Os[b_loc * 97 + vl * 3 + 1] = o1;
    Os[b_loc * 97 + vl * 3 + 2] = o2;
  }
  __syncthreads();   // barrier 2: Os complete

  // ---- store: consecutive lanes -> consecutive dwords (96 per batch row) ----
  const size_t cv3 = (size_t)cV * 3;
  const size_t ob = ((size_t)(mb * 64) * cV + (size_t)nb * 32) * 3;
#pragma unroll
  for (int s = 0; s < 24; ++s) {
    int idx = s * 256 + t;
    int bb = idx / 96, f = idx - bb * 96;
    if (nb < 156 || f < 93)              // nb==156: only 31 valid vertices (93 floats)
      out[ob + (size_t)bb * cv3 + f] = Os[bb * 97 + f];
  }
}

// ---------------- k_lmk: barycentric landmark gather, component-parallel ----
__global__ __launch_bounds__(512) void k_lmk(
    const float* __restrict__ verts, const int* __restrict__ faces,
    const int* __restrict__ lmkf, const float* __restrict__ lmkb,
    const int* __restrict__ dynf, const float* __restrict__ dynb,
    const int* __restrict__ fullf, const float* __restrict__ fullb,
    const int* __restrict__ yrot, float* __restrict__ out) {
  int id = blockIdx.x * 512 + threadIdx.x;
  if (id >= cB * cLF * 6) return;
  int c = id % 3;
  int q = id / 3;
  int sel = q & 1;
  int r = q >> 1;
  int b = r / cLF, l = r - b * cLF;
  const float* vb = verts + (size_t)b * cV * 3;
  int f; float w0, w1, w2; size_t o;
  if (sel == 0) {
    if (l < cLD) {
      int yb = yrot[b];
      f = dynf[yb * cLD + l];
      const float* bp = dynb + ((size_t)yb * cLD + l) * 3;
      w0 = bp[0]; w1 = bp[1]; w2 = bp[2];
    } else {
      f = lmkf[l - cLD];
      const float* bp = lmkb + (size_t)(l - cLD) * 3;
      w0 = bp[0]; w1 = bp[1]; w2 = bp[2];
    }
    o = OUT_V + ((size_t)b * cLF + l) * 3;
  } else {
    f = fullf[l];
    const float* bp = fullb + (size_t)l * 3;
    w0 = bp[0]; w1 = bp[1]; w2 = bp[2];
    o = OUT_V + OUT_L + ((size_t)b * cLF + l) * 3;
  }
  int i0 = faces[f * 3 + 0] * 3, i1 = faces[f * 3 + 1] * 3, i2 = faces[f * 3 + 2] * 3;
  out[o + c] = w0 * vb[i0 + c] + w1 * vb[i1 + c] + w2 * vb[i2 + c];
}

// ---------------- launch: 4 kernels (k_jsred deleted, fused into k_batch) ----
extern "C" void kernel_launch(void* const* d_in, const int* in_sizes, int n_in,
                              void* d_out, int out_size, void* d_ws, size_t ws_size,
                              hipStream_t stream) {
  (void)in_sizes; (void)n_in; (void)out_size; (void)ws_size;
  const float* shp  = (const float*)d_in[0];
  const float* expr = (const float*)d_in[1];
  const float* pose = (const float*)d_in[2];
  const float* eyep = (const float*)d_in[3];
  const float* vt   = (const float*)d_in[4];
  const float* sd   = (const float*)d_in[5];
  const float* pd   = (const float*)d_in[6];
  const float* jreg = (const float*)d_in[7];
  const float* lbw  = (const float*)d_in[8];
  const int*   fcs  = (const int*)d_in[9];
  const int*   lmkf = (const int*)d_in[10];
  const float* lmkb = (const float*)d_in[11];
  const int*   dynf = (const int*)d_in[12];
  const float* dynb = (const float*)d_in[13];
  const int*   fullf= (const int*)d_in[14];
  const float* fullb= (const float*)d_in[15];
  float* out = (float*)d_out;
  float* ws  = (float*)d_ws;

  unsigned int*   btn  = (unsigned int*)(ws + WS_BTN);
  unsigned short* ATm  = (unsigned short*)(ws + WS_ATM);
  float* Arel   = ws + WS_AREL;
  int*   yrot   = (int*)(ws + WS_YROT);
  float* JSpart = ws + WS_JSPART;

  k_aux<<<550, 512, 0, stream>>>(sd, pd, jreg, vt, btn, JSpart);
  k_batch<<<16, 256, 0, stream>>>(shp, expr, pose, eyep, JSpart, Arel, yrot,
                                  (unsigned int*)ATm);
  k_main<<<1256, 256, 0, stream>>>((unsigned short*)btn, ATm, Arel, vt, lbw, out);
  k_lmk<<<408, 512, 0, stream>>>(out, fcs, lmkf, lmkb, dynf, dynb, fullf, fullb, yrot, out);
}

// Round 9
// 173.519 us; speedup vs baseline: 3.4144x; 3.4144x over previous
//
#include <hip/hip_runtime.h>
#include <cstddef>
#include <cstdint>

// ---------------- problem constants ----------------
#define cB   512
#define cV   5023
#define cS   100
#define cE   50
#define cJ   5
#define cLD  17
#define cLF  68

#define cV3    15069       // V*3
#define cNPAD  15072       // 157*96 padded N

#define OUT_V  ((size_t)cB * cV * 3)
#define OUT_L  ((size_t)cB * cLF * 3)

// ws layout (dword offsets)
#define WS_BTN    ((size_t)0)                      // 15072*96 dwords (bf16 x2)
#define WS_ATM    (WS_BTN + (size_t)cNPAD * 96)    // 512*96 dwords
#define WS_JS2    (WS_ATM + 49152)                 // 2432 floats
#define WS_AREL   (WS_JS2 + 2432)                  // 512*60 floats
#define WS_YROT   (WS_AREL + 30720)                // 512 ints
#define WS_JSPART (WS_YROT + 512)                  // 314*2272 floats

typedef __attribute__((ext_vector_type(8))) short short8;
typedef __attribute__((ext_vector_type(4))) float f32x4;

// fp32 -> bf16 round-to-nearest-even
__device__ __forceinline__ unsigned short f2bf(float x) {
  unsigned int u = __float_as_uint(x);
  u = (u + 0x7fffu + ((u >> 16) & 1u)) >> 16;
  return (unsigned short)u;
}

// ---------------- rodrigues (matches jax reference in fp32) ----------------
__device__ __forceinline__ void rodrigues9(float rx, float ry, float rz, float* R) {
  float a0 = rx + 1e-8f, a1 = ry + 1e-8f, a2 = rz + 1e-8f;
  float angle = sqrtf(a0 * a0 + a1 * a1 + a2 * a2);
  float inv = 1.0f / angle;
  float x = rx * inv, y = ry * inv, z = rz * inv;
  float s = sinf(angle), c = cosf(angle);
  float t = 1.0f - c;
  float xy = x * y, xz = x * z, yz = y * z;
  R[0] = 1.0f - t * (y * y + z * z);
  R[1] = -s * z + t * xy;
  R[2] =  s * y + t * xz;
  R[3] =  s * z + t * xy;
  R[4] = 1.0f - t * (x * x + z * z);
  R[5] = -s * x + t * yz;
  R[6] = -s * y + t * xz;
  R[7] =  s * x + t * yz;
  R[8] = 1.0f - t * (x * x + y * y);
}

// ---------------- k_aux: blocks 0..313 JS partials (16 v); 314..549 bf16 BTn rows ----------
__global__ __launch_bounds__(512) void k_aux(
    const float* __restrict__ sd, const float* __restrict__ pd,
    const float* __restrict__ jreg, const float* __restrict__ vt,
    unsigned int* __restrict__ btn_u, float* __restrict__ JSpart) {
  __shared__ __align__(16) unsigned char sm[44032];  // sdt 64*152*4 @0; pdt 64*38*2 @38912
  float* sdt = (float*)sm;
  unsigned short* pdt = (unsigned short*)(sm + 38912);
  const int t = threadIdx.x;
  const int bid = blockIdx.x;
  if (bid < 314) {
    if (t >= 453) return;
    int c = t / 151, l = t - c * 151;
    int v0 = bid * 16;
    float acc[5] = {0.f, 0.f, 0.f, 0.f, 0.f};
#pragma unroll 8
    for (int vi = 0; vi < 16; ++vi) {
      int v = v0 + vi;
      bool ok = (v < cV);
      int vc = ok ? v : 0;
      float x;
      if (l < 150) x = ok ? sd[(size_t)(v * 3 + c) * 150 + l] : 0.f;
      else         x = ok ? vt[v * 3 + c] : 0.f;
#pragma unroll
      for (int j = 0; j < 5; ++j)
        acc[j] = fmaf(jreg[j * cV + vc], x, acc[j]);
    }
#pragma unroll
    for (int j = 0; j < 5; ++j)
      JSpart[(size_t)bid * 2272 + (j * 3 + c) * 151 + l] = acc[j];
  } else {
    const int n0 = (bid - 314) * 64;
    // sd rows (linear, coalesced)
    for (int idx = t; idx < 9600; idx += 512) {
      size_t g = (size_t)n0 * 150 + idx;
      float v = (g < (size_t)cV3 * 150) ? sd[g] : 0.f;
      int row = idx / 150, col = idx - row * 150;
      sdt[row * 152 + col] = v;
    }
    // pd columns (coalesced over n)
    for (int e = t; e < 2304; e += 512) {
      int kk = e >> 6, ln = e & 63;
      int n = n0 + ln;
      pdt[ln * 38 + kk] = f2bf((n < cV3) ? pd[(size_t)kk * cV3 + n] : 0.f);
    }
    __syncthreads();
    // emit BTn rows (96 dwords each), coalesced
    for (int e = t; e < 6144; e += 512) {
      int row = e / 96, d = e - row * 96;
      int n = n0 + row;
      if (n < cNPAD) {
        unsigned int wv;
        if (d < 75) {
          wv = (unsigned int)f2bf(sdt[row * 152 + 2 * d]) |
               ((unsigned int)f2bf(sdt[row * 152 + 2 * d + 1]) << 16);
        } else if (d < 93) {
          int p = (d - 75) * 2;
          wv = (unsigned int)pdt[row * 38 + p] |
               ((unsigned int)pdt[row * 38 + p + 1] << 16);
        } else {
          wv = 0u;
        }
        btn_u[(size_t)n * 96 + d] = wv;
      }
    }
  }
}

// ---------------- k_jsred: 314 partials -> JS2[l][16]; 8 threads per element ----------------
__global__ __launch_bounds__(256) void k_jsred(const float* __restrict__ JSpart,
                                               float* __restrict__ JS2) {
  __shared__ float red[256];
  const int t = threadIdx.x;
  const int e = blockIdx.x * 32 + (t & 31);
  const int pg = t >> 5;
  float s = 0.f;
  if (e < 2265) {
#pragma unroll 8
    for (int p = pg; p < 314; p += 8)
      s += JSpart[(size_t)p * 2272 + e];
  }
  red[t] = s;
  __syncthreads();
  if (t < 128) red[t] += red[t + 128];
  __syncthreads();
  if (t < 64) red[t] += red[t + 64];
  __syncthreads();
  if (t < 32) {
    float v = red[t] + red[t + 32];
    if (e < 2265) {
      int jc = e / 151, l = e - jc * 151;
      JS2[l * 16 + jc] = v;
    }
  }
}

// ---------------- k_batch: joints, rot mats, chain, A_rel, y_rot + ATm bf16 rows ----------
__global__ __launch_bounds__(256) void k_batch(
    const float* __restrict__ shp, const float* __restrict__ expr,
    const float* __restrict__ pose, const float* __restrict__ eyep,
    const float* __restrict__ JS2g, float* __restrict__ Arel,
    int* __restrict__ yrot, unsigned int* __restrict__ atm_u) {
  __shared__ float js2[151 * 16];
  __shared__ float sb[32 * 153];
  __shared__ float pfs[32 * 36];
  const int t = threadIdx.x;
  const int b0 = blockIdx.x * 32;
  for (int i = t; i < 151 * 16; i += 256) js2[i] = JS2g[i];
  for (int e = t; e < 3200; e += 256) {
    int bl = e / 100, l = e - bl * 100;
    sb[bl * 153 + l] = shp[(size_t)(b0 + bl) * 100 + l];
  }
  for (int e = t; e < 1600; e += 256) {
    int bl = e / 50, l = e - bl * 50;
    sb[bl * 153 + 100 + l] = expr[(size_t)(b0 + bl) * 50 + l];
  }
  __syncthreads();

  if (t < 32) {
    int b = b0 + t;
    float jnt[5][3];
    {
      const f32x4* J4 = (const f32x4*)(js2 + 150 * 16);
      f32x4 A = J4[0], Bq = J4[1], Cq = J4[2], Dq = J4[3];
      jnt[0][0] = A.x;  jnt[0][1] = A.y;  jnt[0][2] = A.z;
      jnt[1][0] = A.w;  jnt[1][1] = Bq.x; jnt[1][2] = Bq.y;
      jnt[2][0] = Bq.z; jnt[2][1] = Bq.w; jnt[2][2] = Cq.x;
      jnt[3][0] = Cq.y; jnt[3][1] = Cq.z; jnt[3][2] = Cq.w;
      jnt[4][0] = Dq.x; jnt[4][1] = Dq.y; jnt[4][2] = Dq.z;
    }
    for (int l = 0; l < 150; ++l) {
      const f32x4* J4 = (const f32x4*)(js2 + l * 16);
      f32x4 A = J4[0], Bq = J4[1], Cq = J4[2], Dq = J4[3];
      float beta = sb[t * 153 + l];
      jnt[0][0] = fmaf(beta, A.x,  jnt[0][0]);
      jnt[0][1] = fmaf(beta, A.y,  jnt[0][1]);
      jnt[0][2] = fmaf(beta, A.z,  jnt[0][2]);
      jnt[1][0] = fmaf(beta, A.w,  jnt[1][0]);
      jnt[1][1] = fmaf(beta, Bq.x, jnt[1][1]);
      jnt[1][2] = fmaf(beta, Bq.y, jnt[1][2]);
      jnt[2][0] = fmaf(beta, Bq.z, jnt[2][0]);
      jnt[2][1] = fmaf(beta, Bq.w, jnt[2][1]);
      jnt[2][2] = fmaf(beta, Cq.x, jnt[2][2]);
      jnt[3][0] = fmaf(beta, Cq.y, jnt[3][0]);
      jnt[3][1] = fmaf(beta, Cq.z, jnt[3][1]);
      jnt[3][2] = fmaf(beta, Cq.w, jnt[3][2]);
      jnt[4][0] = fmaf(beta, Dq.x, jnt[4][0]);
      jnt[4][1] = fmaf(beta, Dq.y, jnt[4][1]);
      jnt[4][2] = fmaf(beta, Dq.z, jnt[4][2]);
    }
    float fp[5][3];
    fp[0][0] = pose[b * 6 + 0]; fp[0][1] = pose[b * 6 + 1]; fp[0][2] = pose[b * 6 + 2];
    fp[1][0] = 0.f; fp[1][1] = 0.f; fp[1][2] = 0.f;
    fp[2][0] = pose[b * 6 + 3]; fp[2][1] = pose[b * 6 + 4]; fp[2][2] = pose[b * 6 + 5];
    fp[3][0] = eyep[b * 6 + 0]; fp[3][1] = eyep[b * 6 + 1]; fp[3][2] = eyep[b * 6 + 2];
    fp[4][0] = eyep[b * 6 + 3]; fp[4][1] = eyep[b * 6 + 4]; fp[4][2] = eyep[b * 6 + 5];
    float R[5][9];
#pragma unroll
    for (int j = 0; j < 5; ++j) rodrigues9(fp[j][0], fp[j][1], fp[j][2], R[j]);
#pragma unroll
    for (int j = 1; j < 5; ++j)
#pragma unroll
      for (int r = 0; r < 9; ++r) {
        float id = (r == 0 || r == 4 || r == 8) ? 1.f : 0.f;
        pfs[t * 36 + (j - 1) * 9 + r] = R[j][r] - id;
      }
    float rel[5][3];
#pragma unroll
    for (int c = 0; c < 3; ++c) {
      rel[0][c] = jnt[0][c];
      rel[1][c] = jnt[1][c] - jnt[0][c];
      rel[2][c] = jnt[2][c] - jnt[1][c];
      rel[3][c] = jnt[3][c] - jnt[1][c];
      rel[4][c] = jnt[4][c] - jnt[1][c];
    }
    float GR[5][9], Gt[5][3];
#pragma unroll
    for (int r = 0; r < 9; ++r) GR[0][r] = R[0][r];
#pragma unroll
    for (int c = 0; c < 3; ++c) Gt[0][c] = rel[0][c];
    const int par[5] = {0, 0, 1, 1, 1};
#pragma unroll
    for (int j = 1; j < 5; ++j) {
      int p = par[j];
#pragma unroll
      for (int r = 0; r < 3; ++r) {
#pragma unroll
        for (int cc = 0; cc < 3; ++cc)
          GR[j][r * 3 + cc] = GR[p][r * 3 + 0] * R[j][0 + cc] +
                              GR[p][r * 3 + 1] * R[j][3 + cc] +
                              GR[p][r * 3 + 2] * R[j][6 + cc];
        Gt[j][r] = Gt[p][r] + GR[p][r * 3 + 0] * rel[j][0] +
                              GR[p][r * 3 + 1] * rel[j][1] +
                              GR[p][r * 3 + 2] * rel[j][2];
      }
    }
#pragma unroll
    for (int j = 0; j < 5; ++j)
#pragma unroll
      for (int r = 0; r < 3; ++r) {
        float tj = Gt[j][r] - (GR[j][r * 3 + 0] * jnt[j][0] +
                               GR[j][r * 3 + 1] * jnt[j][1] +
                               GR[j][r * 3 + 2] * jnt[j][2]);
        Arel[b * 60 + j * 12 + r * 4 + 0] = GR[j][r * 3 + 0];
        Arel[b * 60 + j * 12 + r * 4 + 1] = GR[j][r * 3 + 1];
        Arel[b * 60 + j * 12 + r * 4 + 2] = GR[j][r * 3 + 2];
        Arel[b * 60 + j * 12 + r * 4 + 3] = tj;
      }
    float Ra[9], Rb[9];
    rodrigues9(fp[1][0], fp[1][1], fp[1][2], Ra);
    rodrigues9(fp[0][0], fp[0][1], fp[0][2], Rb);
    float r00 = Rb[0] * Ra[0] + Rb[1] * Ra[3] + Rb[2] * Ra[6];
    float r10 = Rb[3] * Ra[0] + Rb[4] * Ra[3] + Rb[5] * Ra[6];
    float r20 = Rb[6] * Ra[0] + Rb[7] * Ra[3] + Rb[8] * Ra[6];
    float sy = sqrtf(r00 * r00 + r10 * r10);
    float ydeg = atan2f(-r20, sy) * 57.29577951308232f;
    int y = (int)rintf(fminf(ydeg, 39.0f));
    if (y < 0) y = (y < -39) ? 78 : (39 - y);
    yrot[b] = y;
  }
  __syncthreads();

#pragma unroll
  for (int it = 0; it < 12; ++it) {
    int e = t + it * 256;
    int bl = e / 96, d = e - bl * 96;
    unsigned int wv;
    if (d < 75) {
      wv = (unsigned int)f2bf(sb[bl * 153 + 2 * d]) |
           ((unsigned int)f2bf(sb[bl * 153 + 2 * d + 1]) << 16);
    } else if (d < 93) {
      wv = (unsigned int)f2bf(pfs[bl * 36 + (d - 75) * 2]) |
           ((unsigned int)f2bf(pfs[bl * 36 + (d - 75) * 2 + 1]) << 16);
    } else {
      wv = 0u;
    }
    atm_u[(size_t)(b0 + bl) * 96 + d] = wv;
  }
}

// ---------------- k_main (r5 best measured): barrier-light GEMM with depth-3
// load ring, direct-global fragments, Os-staged coalesced stores.
// 1256 blocks = 157 nb x 8 mb (nb-adjacent same-XCD), two barriers total.
__global__ __launch_bounds__(256) void k_main(
    const unsigned short* __restrict__ BTn, const unsigned short* __restrict__ ATm,
    const float* __restrict__ Arel, const float* __restrict__ vtempl,
    const float* __restrict__ lbw, float* __restrict__ out) {
  __shared__ float Pf[96 * 66];         // 25,344 B: GEMM result, [n_loc][b] transpose
  __shared__ float Os[64 * 97];         // 24,832 B: out stage, stride 97
  __shared__ float lbwT[160];           // 32 v x 5 j
  __shared__ float vtT[96];             // 32 v x 3 c

  const int bid = blockIdx.x;           // 1256 = 157 * 8
  const int nb = bid >> 3, mb = bid & 7;

  const int t = threadIdx.x;
  const int w = t >> 6, L = t & 63;
  const int wm = w >> 1, wn = w & 1;
  const int lr = L & 15, lq = L >> 4;

  // small tiles to LDS (covered by barrier 1)
  if (t < 160) {
    int vl = t / 5, j = t - vl * 5;
    int v = nb * 32 + vl;
    lbwT[t] = (v < cV) ? lbw[v * 5 + j] : 0.f;
  }
  if (t >= 160 && t < 256) {
    int e = t - 160;
    int vl = e / 3, c = e - vl * 3;
    int v = nb * 32 + vl;
    vtT[e] = (v < cV) ? vtempl[v * 3 + c] : 0.f;
  }

  // ---- GEMM: direct-global fragments, depth-3 rolling ring ----
  const unsigned short* abase = ATm + ((size_t)mb * 64 + wm * 32 + lr) * 192 + lq * 8;
  const unsigned short* bbase = BTn + ((size_t)nb * 96 + wn * 48 + lr) * 192 + lq * 8;

  f32x4 acc[2][3];
#pragma unroll
  for (int mt = 0; mt < 2; ++mt)
#pragma unroll
    for (int nt = 0; nt < 3; ++nt) acc[mt][nt] = (f32x4){0.f, 0.f, 0.f, 0.f};

  short8 A0[3], A1[3], B0[3], B1[3], B2[3];   // ring: 15 x short8 = 60 VGPR
#pragma unroll
  for (int d = 0; d < 3; ++d) {
    const int ko = d * 32;
    A0[d] = *(const short8*)(abase + ko);
    A1[d] = *(const short8*)(abase + 16 * 192 + ko);
    B0[d] = *(const short8*)(bbase + ko);
    B1[d] = *(const short8*)(bbase + 16 * 192 + ko);
    B2[d] = *(const short8*)(bbase + 32 * 192 + ko);
  }
#pragma unroll
  for (int ks = 0; ks < 6; ++ks) {
    const int d = ks % 3;                     // static after full unroll
    short8 a0 = A0[d], a1 = A1[d], b0 = B0[d], b1 = B1[d], b2 = B2[d];
    if (ks < 3) {                             // refill ring slot for ks+3
      const int ko = (ks + 3) * 32;
      A0[d] = *(const short8*)(abase + ko);
      A1[d] = *(const short8*)(abase + 16 * 192 + ko);
      B0[d] = *(const short8*)(bbase + ko);
      B1[d] = *(const short8*)(bbase + 16 * 192 + ko);
      B2[d] = *(const short8*)(bbase + 32 * 192 + ko);
    }
    acc[0][0] = __builtin_amdgcn_mfma_f32_16x16x32_bf16(a0, b0, acc[0][0], 0, 0, 0);
    acc[1][0] = __builtin_amdgcn_mfma_f32_16x16x32_bf16(a1, b0, acc[1][0], 0, 0, 0);
    acc[0][1] = __builtin_amdgcn_mfma_f32_16x16x32_bf16(a0, b1, acc[0][1], 0, 0, 0);
    acc[1][1] = __builtin_amdgcn_mfma_f32_16x16x32_bf16(a1, b1, acc[1][1], 0, 0, 0);
    acc[0][2] = __builtin_amdgcn_mfma_f32_16x16x32_bf16(a0, b2, acc[0][2], 0, 0, 0);
    acc[1][2] = __builtin_amdgcn_mfma_f32_16x16x32_bf16(a1, b2, acc[1][2], 0, 0, 0);
  }

  // ---- acc -> Pf[n_loc][b] (stride 66: conflict-free both directions) ----
#pragma unroll
  for (int mt = 0; mt < 2; ++mt)
#pragma unroll
    for (int nt = 0; nt < 3; ++nt) {
      int n_loc = wn * 48 + nt * 16 + lr;
      int m = wm * 32 + mt * 16 + lq * 4;
      *(f32x4*)(Pf + n_loc * 66 + m) = acc[mt][nt];
    }

  // ---- Arel rows: issue before the barrier; L2 latency overlaps barrier wait ----
  const int b_loc = t >> 2, part = t & 3;
  const float* qb = Arel + ((size_t)mb * 64 + b_loc) * 60;
  f32x4 ar[15];
#pragma unroll
  for (int r = 0; r < 15; ++r) ar[r] = *(const f32x4*)(qb + 4 * r);

  __syncthreads();   // barrier 1: Pf/lbwT/vtT visible

  // ---- b-major LBS epilogue -> Os ----
#pragma unroll
  for (int ii = 0; ii < 8; ++ii) {
    const int vl = part * 8 + ii;
    float px = Pf[(vl * 3 + 0) * 66 + b_loc] + vtT[vl * 3 + 0];
    float py = Pf[(vl * 3 + 1) * 66 + b_loc] + vtT[vl * 3 + 1];
    float pz = Pf[(vl * 3 + 2) * 66 + b_loc] + vtT[vl * 3 + 2];
    float o0 = 0.f, o1 = 0.f, o2 = 0.f;
#pragma unroll
    for (int j = 0; j < 5; ++j) {
      f32x4 q0 = ar[3 * j + 0], q1 = ar[3 * j + 1], q2 = ar[3 * j + 2];
      float s0 = q0.x * px + q0.y * py + q0.z * pz + q0.w;
      float s1 = q1.x * px + q1.y * py + q1.z * pz + q1.w;
      float s2 = q2.x * px + q2.y * py + q2.z * pz + q2.w;
      float wj = lbwT[vl * 5 + j];
      o0 = fmaf(wj, s0, o0);
      o1 = fmaf(wj, s1, o1);
      o2 = fmaf(wj, s2, o2);
    }
    Os[b_loc * 97 + vl * 3 + 0] = o0;
    Os[b_loc * 97 + vl * 3 + 1] = o1;
    Os[b_loc * 97 + vl * 3 + 2] = o2;
  }
  __syncthreads();   // barrier 2: Os complete

  // ---- store: consecutive lanes -> consecutive dwords (96 per batch row) ----
  const size_t cv3 = (size_t)cV * 3;
  const size_t ob = ((size_t)(mb * 64) * cV + (size_t)nb * 32) * 3;
#pragma unroll
  for (int s = 0; s < 24; ++s) {
    int idx = s * 256 + t;
    int bb = idx / 96, f = idx - bb * 96;
    if (nb < 156 || f < 93)              // nb==156: only 31 valid vertices (93 floats)
      out[ob + (size_t)bb * cv3 + f] = Os[bb * 97 + f];
  }
}

// ---------------- k_lmk: barycentric landmark gather, component-parallel ----
__global__ __launch_bounds__(512) void k_lmk(
    const float* __restrict__ verts, const int* __restrict__ faces,
    const int* __restrict__ lmkf, const float* __restrict__ lmkb,
    const int* __restrict__ dynf, const float* __restrict__ dynb,
    const int* __restrict__ fullf, const float* __restrict__ fullb,
    const int* __restrict__ yrot, float* __restrict__ out) {
  int id = blockIdx.x * 512 + threadIdx.x;
  if (id >= cB * cLF * 6) return;
  int c = id % 3;
  int q = id / 3;
  int sel = q & 1;
  int r = q >> 1;
  int b = r / cLF, l = r - b * cLF;
  const float* vb = verts + (size_t)b * cV * 3;
  int f; float w0, w1, w2; size_t o;
  if (sel == 0) {
    if (l < cLD) {
      int yb = yrot[b];
      f = dynf[yb * cLD + l];
      const float* bp = dynb + ((size_t)yb * cLD + l) * 3;
      w0 = bp[0]; w1 = bp[1]; w2 = bp[2];
    } else {
      f = lmkf[l - cLD];
      const float* bp = lmkb + (size_t)(l - cLD) * 3;
      w0 = bp[0]; w1 = bp[1]; w2 = bp[2];
    }
    o = OUT_V + ((size_t)b * cLF + l) * 3;
  } else {
    f = fullf[l];
    const float* bp = fullb + (size_t)l * 3;
    w0 = bp[0]; w1 = bp[1]; w2 = bp[2];
    o = OUT_V + OUT_L + ((size_t)b * cLF + l) * 3;
  }
  int i0 = faces[f * 3 + 0] * 3, i1 = faces[f * 3 + 1] * 3, i2 = faces[f * 3 + 2] * 3;
  out[o + c] = w0 * vb[i0 + c] + w1 * vb[i1 + c] + w2 * vb[i2 + c];
}

// ---------------- launch ----------------
extern "C" void kernel_launch(void* const* d_in, const int* in_sizes, int n_in,
                              void* d_out, int out_size, void* d_ws, size_t ws_size,
                              hipStream_t stream) {
  (void)in_sizes; (void)n_in; (void)out_size; (void)ws_size;
  const float* shp  = (const float*)d_in[0];
  const float* expr = (const float*)d_in[1];
  const float* pose = (const float*)d_in[2];
  const float* eyep = (const float*)d_in[3];
  const float* vt   = (const float*)d_in[4];
  const float* sd   = (const float*)d_in[5];
  const float* pd   = (const float*)d_in[6];
  const float* jreg = (const float*)d_in[7];
  const float* lbw  = (const float*)d_in[8];
  const int*   fcs  = (const int*)d_in[9];
  const int*   lmkf = (const int*)d_in[10];
  const float* lmkb = (const float*)d_in[11];
  const int*   dynf = (const int*)d_in[12];
  const float* dynb = (const float*)d_in[13];
  const int*   fullf= (const int*)d_in[14];
  const float* fullb= (const float*)d_in[15];
  float* out = (float*)d_out;
  float* ws  = (float*)d_ws;

  unsigned int*   btn  = (unsigned int*)(ws + WS_BTN);
  unsigned short* ATm  = (unsigned short*)(ws + WS_ATM);
  float* JS2    = ws + WS_JS2;
  float* Arel   = ws + WS_AREL;
  int*   yrot   = (int*)(ws + WS_YROT);
  float* JSpart = ws + WS_JSPART;

  k_aux<<<550, 512, 0, stream>>>(sd, pd, jreg, vt, btn, JSpart);
  k_jsred<<<71, 256, 0, stream>>>(JSpart, JS2);
  k_batch<<<16, 256, 0, stream>>>(shp, expr, pose, eyep, JS2, Arel, yrot,
                                  (unsigned int*)ATm);
  k_main<<<1256, 256, 0, stream>>>((unsigned short*)btn, ATm, Arel, vt, lbw, out);
  k_lmk<<<408, 512, 0, stream>>>(out, fcs, lmkf, lmkb, dynf, dynb, fullf, fullb, yrot, out);
}